// Round 2
// baseline (243.945 us; speedup 1.0000x reference)
//
#include <hip/hip_runtime.h>
#include <math.h>

#define BB 16
#define SS 256
#define CC 17
#define NCH 16
#define DD 32
#define DFFN 64
#define HH 4
#define DH 8
#define EE 4

// ws layout (floats):
//  [16 ..143]  K0[e][d]   [144..271] V0[e][d]
//  [512..]     XNS[b][s][n]  (B*S*NCH)
//  ints at WS_SPI: SP[b][t] (4096), then OFF[b][e] (64)
#define WS_K0 16
#define WS_V0 144
#define WS_XNS 512
#define WS_SPI (WS_XNS + BB*SS*NCH)

// ---------------------------------------------------------------------------
// Kernel 1: seasonal-trend decomposition per (b, channel n<16).
// Rotator-recurrence DFT (no LDS cos table -> no bank conflicts),
// parallel argmax top-4 (no serial thread-0 scan).
// ---------------------------------------------------------------------------
__global__ void decomp_kernel(const float* __restrict__ x, float* __restrict__ ws) {
  const int b = blockIdx.x / NCH;
  const int c = blockIdx.x % NCH;
  const int t = threadIdx.x;  // 256
  __shared__ float xs[SS];
  __shared__ float Xr[129], Xi[129], amp[129];
  __shared__ float redv[128];
  __shared__ int   redi[128];
  __shared__ float sth;
  xs[t] = x[(b*SS + t)*CC + c];
  __syncthreads();
  const float TH0 = 0.024543692606170259f;  // 2*pi/256
  float a = -1e30f;
  if (t < 128) {
    const int f = t + 1;   // freqs 1..128 (f=0 excluded: amp[0]=-inf in ref)
    float s1, c1; sincosf((float)f * TH0, &s1, &c1);
    float cr = 1.f, si = 0.f, xr = 0.f, xi = 0.f;
    for (int s2 = 0; s2 < SS; ++s2) {
      float xvv = xs[s2];
      xr += xvv * cr;
      xi -= xvv * si;
      float nc = cr*c1 - si*s1;
      si = si*c1 + cr*s1;
      cr = nc;
    }
    Xr[f] = xr; Xi[f] = xi;
    float am = sqrtf(xr*xr + xi*xi);
    amp[f] = am;
    a = am;
  }
  __syncthreads();
  // parallel top-4 (argmax, knock out one instance per round; thresh = 4th value)
  for (int p = 0; p < 4; ++p) {
    if (t < 128) { redv[t] = a; redi[t] = t; }
    __syncthreads();
    for (int off = 64; off > 0; off >>= 1) {
      if (t < off && redv[t+off] > redv[t]) { redv[t] = redv[t+off]; redi[t] = redi[t+off]; }
      __syncthreads();
    }
    if (t == 0 && p == 3) sth = redv[0];
    if (t < 128 && t == redi[0]) a = -1e30f;
    __syncthreads();
  }
  const float th = sth;
  // season: masked irfft at s=t, rotator over f
  float s1, c1; sincosf((float)t * TH0, &s1, &c1);
  float cr = c1, si = s1, acc = 0.f;
  for (int f = 1; f <= 128; ++f) {
    float wgt = (amp[f] >= th) ? ((f == 128) ? 1.0f : 2.0f) : 0.0f;
    acc += wgt * (Xr[f]*cr - Xi[f]*si);
    float nc = cr*c1 - si*s1;
    si = si*c1 + cr*s1;
    cr = nc;
  }
  float season = acc * (1.0f / 256.0f);
  // trend: mean of moving averages k=4,8,12 with edge-replicate padding
  float s4 = 0.f, s8 = 0.f, s12 = 0.f;
  #pragma unroll
  for (int j = 0; j < 4; ++j)  { int p = t + j - 1; p = p < 0 ? 0 : (p > SS-1 ? SS-1 : p); s4  += xs[p]; }
  #pragma unroll
  for (int j = 0; j < 8; ++j)  { int p = t + j - 3; p = p < 0 ? 0 : (p > SS-1 ? SS-1 : p); s8  += xs[p]; }
  #pragma unroll
  for (int j = 0; j < 12; ++j) { int p = t + j - 5; p = p < 0 ? 0 : (p > SS-1 ? SS-1 : p); s12 += xs[p]; }
  float trend = (s4 * 0.25f + s8 * 0.125f + s12 * (1.0f/12.0f)) * (1.0f/3.0f);
  ws[WS_XNS + (b*SS + t)*NCH + c] = xs[t] + season + trend;
}

// ---------------------------------------------------------------------------
// Kernel 2: fused prep — global min/max, assignment + expert-sorted lists,
// per-expert k0/v0. One block, 1024 threads.
// ---------------------------------------------------------------------------
__global__ void prep_kernel(const float* __restrict__ ox, const float* __restrict__ sb,
                            const float* __restrict__ g1, const float* __restrict__ bb1,
                            const float* __restrict__ Wk, const float* __restrict__ Wv,
                            float* __restrict__ ws) {
  const int t = threadIdx.x;  // 1024
  __shared__ float rmn[1024], rmx[1024];
  __shared__ int asg[BB*SS];
  __shared__ int cnt[64];
  __shared__ float z0[EE*DD];
  __shared__ float sbmin, sbmax;
  float mn = 3e38f, mx = -3e38f;
  #pragma unroll
  for (int k = 0; k < 4; ++k) {
    float v = ox[(t + k*1024)*2 + 1];
    mn = fminf(mn, v); mx = fmaxf(mx, v);
  }
  rmn[t] = mn; rmx[t] = mx;
  __syncthreads();
  for (int off = 512; off > 0; off >>= 1) {
    if (t < off) { rmn[t] = fminf(rmn[t], rmn[t+off]); rmx[t] = fmaxf(rmx[t], rmx[t+off]); }
    __syncthreads();
  }
  if (t == 0) { sbmin = rmn[0]; sbmax = rmx[0]; }
  __syncthreads();
  const float step = (sbmax - sbmin) * 0.25f;
  const float e1 = sbmin + step, e2 = sbmin + step*2.f, e3 = sbmin + step*3.f;
  #pragma unroll
  for (int k = 0; k < 4; ++k) {
    int i = t + k*1024;
    float sc = ox[i*2 + 1];
    asg[i] = (sc >= e1) + (sc >= e2) + (sc >= e3);
  }
  __syncthreads();
  if (t < 64) {
    int bb = t >> 2, ee = t & 3, c = 0;
    for (int s2 = 0; s2 < SS; ++s2) c += (asg[bb*SS + s2] == ee);
    cnt[t] = c;
  }
  __syncthreads();
  int* SPw  = (int*)ws + WS_SPI;
  int* OFFw = SPw + BB*SS;
  if (t < 64) {
    int bb = t >> 2, ee = t & 3;
    int off = 0;
    for (int e2i = 0; e2i < ee; ++e2i) off += cnt[bb*4 + e2i];
    OFFw[bb*4 + ee] = off;
    int kp = off;
    for (int s2 = 0; s2 < SS; ++s2) if (asg[bb*SS + s2] == ee) SPw[bb*SS + (kp++)] = s2;
  }
  // k0/v0: LN(start_b) through Wk/Wv per expert
  if (t < 128) {
    int ee = t >> 5, d = t & 31;
    float m = 0.f;
    for (int i = 0; i < DD; ++i) m += sb[i];
    m *= (1.0f/DD);
    float var = 0.f;
    for (int i = 0; i < DD; ++i) { float df = sb[i]-m; var += df*df; }
    var *= (1.0f/DD);
    float rs = rsqrtf(var + 1e-5f);
    z0[ee*DD + d] = (sb[d]-m)*rs*g1[ee*DD+d] + bb1[ee*DD+d];
  }
  __syncthreads();
  if (t < 128) {
    int ee = t >> 5, d = t & 31;
    float k0 = 0.f, v0 = 0.f;
    for (int i = 0; i < DD; ++i) {
      float zz = z0[ee*DD + i];
      k0 += zz * Wk[ee*DD*DD + i*DD + d];
      v0 += zz * Wv[ee*DD*DD + i*DD + d];
    }
    ws[WS_K0 + ee*DD + d] = k0;
    ws[WS_V0 + ee*DD + d] = v0;
  }
}

// ---------------------------------------------------------------------------
// Kernel 3: fused expert forward. One block per (b,n), 1024 threads:
// thread = (sorted-position p, head hh). k/v LDS stride 36 (aligned, <=2-way).
// ---------------------------------------------------------------------------
#define KSTR 36
#define FSTR 65
#define VBASE (SS*KSTR)          // 9216
#define BUFSZ (2*SS*KSTR)        // 18432 floats = 72 KB

__launch_bounds__(1024, 4)
__global__ void expert_kernel(const float* __restrict__ ws,
    const float* __restrict__ sW, const float* __restrict__ sb,
    const float* __restrict__ Wq, const float* __restrict__ Wk,
    const float* __restrict__ Wv, const float* __restrict__ Wo,
    const float* __restrict__ g1, const float* __restrict__ bb1,
    const float* __restrict__ g2, const float* __restrict__ bb2,
    const float* __restrict__ W1, const float* __restrict__ b1,
    const float* __restrict__ W2, const float* __restrict__ b2,
    float* __restrict__ out) {
  const int b = blockIdx.x / NCH;
  const int n = blockIdx.x % NCH;
  const int t = threadIdx.x;
  const int p = t >> 2;      // sorted position index
  const int hh = t & 3;      // head
  __shared__ float buf[BUFSZ];
  const int* SP  = (const int*)ws + WS_SPI;
  const int* OFF = SP + BB*SS;
  const int o1 = OFF[b*4+1], o2 = OFF[b*4+2], o3 = OFF[b*4+3];
  const int e = (p >= o1) + (p >= o2) + (p >= o3);
  const int beg = (e==0) ? 0  : ((e==1) ? o1 : ((e==2) ? o2 : o3));
  const int end = (e==0) ? o1 : ((e==1) ? o2 : ((e==2) ? o3 : SS));
  const int s = SP[b*SS + p];
  const float xv = ws[WS_XNS + (b*SS + s)*NCH + n];

  float h[DD];
  #pragma unroll
  for (int d = 0; d < DD; ++d) h[d] = xv * sW[d] + sb[d];
  // LN1 (replicated across the 4 head-threads of a position; cheap)
  float m = 0.f;
  #pragma unroll
  for (int d = 0; d < DD; ++d) m += h[d];
  m *= (1.0f/DD);
  float var = 0.f;
  #pragma unroll
  for (int d = 0; d < DD; ++d) { float df = h[d]-m; var += df*df; }
  var *= (1.0f/DD);
  float rs = rsqrtf(var + 1e-5f);
  float z[DD];
  #pragma unroll
  for (int d = 0; d < DD; ++d) z[d] = (h[d]-m)*rs*g1[e*DD+d] + bb1[e*DD+d];

  // q/k/v for this head's 8-column slice
  const float* wqp = Wq + e*DD*DD + hh*DH;
  const float* wkp = Wk + e*DD*DD + hh*DH;
  const float* wvp = Wv + e*DD*DD + hh*DH;
  float q[DH]  = {0,0,0,0,0,0,0,0};
  float kk[DH] = {0,0,0,0,0,0,0,0};
  float vv[DH] = {0,0,0,0,0,0,0,0};
  #pragma unroll
  for (int i = 0; i < DD; ++i) {
    float zz = z[i];
    float4 a0 = *(const float4*)(wqp + i*DD);
    float4 a1 = *(const float4*)(wqp + i*DD + 4);
    q[0]+=zz*a0.x; q[1]+=zz*a0.y; q[2]+=zz*a0.z; q[3]+=zz*a0.w;
    q[4]+=zz*a1.x; q[5]+=zz*a1.y; q[6]+=zz*a1.z; q[7]+=zz*a1.w;
    float4 b0 = *(const float4*)(wkp + i*DD);
    float4 b1v = *(const float4*)(wkp + i*DD + 4);
    kk[0]+=zz*b0.x; kk[1]+=zz*b0.y; kk[2]+=zz*b0.z; kk[3]+=zz*b0.w;
    kk[4]+=zz*b1v.x; kk[5]+=zz*b1v.y; kk[6]+=zz*b1v.z; kk[7]+=zz*b1v.w;
    float4 c0 = *(const float4*)(wvp + i*DD);
    float4 c1v = *(const float4*)(wvp + i*DD + 4);
    vv[0]+=zz*c0.x; vv[1]+=zz*c0.y; vv[2]+=zz*c0.z; vv[3]+=zz*c0.w;
    vv[4]+=zz*c1v.x; vv[5]+=zz*c1v.y; vv[6]+=zz*c1v.z; vv[7]+=zz*c1v.w;
  }
  #pragma unroll
  for (int d = 0; d < DH; ++d) buf[p*KSTR + hh*DH + d] = kk[d];
  #pragma unroll
  for (int d = 0; d < DH; ++d) buf[VBASE + p*KSTR + hh*DH + d] = vv[d];
  __syncthreads();

  const float scale = 0.35355339059327373f;  // 1/sqrt(8)
  float s0 = 0.f;
  #pragma unroll
  for (int d = 0; d < DH; ++d) s0 += q[d] * ws[WS_K0 + e*DD + hh*DH + d];
  s0 *= scale;
  float wsum = 0.f;
  float o[DH] = {0,0,0,0,0,0,0,0};
  for (int j = beg; j < end; ++j) {
    const float* kr = &buf[j*KSTR + hh*DH];
    const float* vr = &buf[VBASE + j*KSTR + hh*DH];
    float a = 0.f;
    #pragma unroll
    for (int d = 0; d < DH; ++d) a += q[d] * kr[d];
    float w = __expf(a * scale);
    wsum += w;
    #pragma unroll
    for (int d = 0; d < DH; ++d) o[d] += w * vr[d];
  }
  // (S - c_e) off-expert keys: constant score s0, constant value v0
  const int nmis = SS - (end - beg);
  float w0 = (float)nmis * __expf(s0);
  wsum += w0;
  #pragma unroll
  for (int d = 0; d < DH; ++d) o[d] += w0 * ws[WS_V0 + e*DD + hh*DH + d];
  float inv = 1.0f / wsum;
  #pragma unroll
  for (int d = 0; d < DH; ++d) o[d] *= inv;
  __syncthreads();

  // share o (full 32 per position) via k-region
  #pragma unroll
  for (int d = 0; d < DH; ++d) buf[p*KSTR + hh*DH + d] = o[d];
  __syncthreads();
  // Wo slice: this thread computes output dims [hh*8, hh*8+8)
  const float* wop = Wo + e*DD*DD + hh*DH;
  float acc[DH] = {0,0,0,0,0,0,0,0};
  #pragma unroll
  for (int i = 0; i < DD; ++i) {
    float ov = buf[p*KSTR + i];
    float4 a0 = *(const float4*)(wop + i*DD);
    float4 a1 = *(const float4*)(wop + i*DD + 4);
    acc[0]+=ov*a0.x; acc[1]+=ov*a0.y; acc[2]+=ov*a0.z; acc[3]+=ov*a0.w;
    acc[4]+=ov*a1.x; acc[5]+=ov*a1.y; acc[6]+=ov*a1.z; acc[7]+=ov*a1.w;
  }
  #pragma unroll
  for (int d = 0; d < DH; ++d) buf[VBASE + p*KSTR + hh*DH + d] = h[hh*DH + d] + acc[d];
  __syncthreads();
  #pragma unroll
  for (int i = 0; i < DD; ++i) h[i] = buf[VBASE + p*KSTR + i];
  // LN2
  m = 0.f;
  #pragma unroll
  for (int d = 0; d < DD; ++d) m += h[d];
  m *= (1.0f/DD);
  var = 0.f;
  #pragma unroll
  for (int d = 0; d < DD; ++d) { float df = h[d]-m; var += df*df; }
  var *= (1.0f/DD);
  rs = rsqrtf(var + 1e-5f);
  #pragma unroll
  for (int d = 0; d < DD; ++d) z[d] = (h[d]-m)*rs*g2[e*DD+d] + bb2[e*DD+d];
  __syncthreads();   // everyone has read their h before f overwrites buf

  // FFN1: this thread computes f[hh*16 .. hh*16+16)
  const float* w1p = W1 + e*DD*DFFN + hh*16;
  float f[16];
  #pragma unroll
  for (int j = 0; j < 16; ++j) f[j] = 0.f;
  #pragma unroll
  for (int i = 0; i < DD; ++i) {
    float zz = z[i];
    float4 a0 = *(const float4*)(w1p + i*DFFN);
    float4 a1 = *(const float4*)(w1p + i*DFFN + 4);
    float4 a2 = *(const float4*)(w1p + i*DFFN + 8);
    float4 a3 = *(const float4*)(w1p + i*DFFN + 12);
    f[0]+=zz*a0.x; f[1]+=zz*a0.y; f[2]+=zz*a0.z; f[3]+=zz*a0.w;
    f[4]+=zz*a1.x; f[5]+=zz*a1.y; f[6]+=zz*a1.z; f[7]+=zz*a1.w;
    f[8]+=zz*a2.x; f[9]+=zz*a2.y; f[10]+=zz*a2.z; f[11]+=zz*a2.w;
    f[12]+=zz*a3.x; f[13]+=zz*a3.y; f[14]+=zz*a3.z; f[15]+=zz*a3.w;
  }
  #pragma unroll
  for (int j = 0; j < 16; ++j) {
    f[j] = fmaxf(f[j] + b1[e*DFFN + hh*16 + j], 0.0f);
    buf[p*FSTR + hh*16 + j] = f[j];
  }
  __syncthreads();
  // FFN2 + residual + b2, output dims [hh*8, hh*8+8)
  const float* w2p = W2 + e*DFFN*DD + hh*DH;
  float acc2[DH];
  #pragma unroll
  for (int d = 0; d < DH; ++d) acc2[d] = h[hh*DH + d] + b2[e*DD + hh*DH + d];
  #pragma unroll
  for (int j = 0; j < DFFN; ++j) {
    float fj = buf[p*FSTR + j];
    float4 a0 = *(const float4*)(w2p + j*DD);
    float4 a1 = *(const float4*)(w2p + j*DD + 4);
    acc2[0]+=fj*a0.x; acc2[1]+=fj*a0.y; acc2[2]+=fj*a0.z; acc2[3]+=fj*a0.w;
    acc2[4]+=fj*a1.x; acc2[5]+=fj*a1.y; acc2[6]+=fj*a1.z; acc2[7]+=fj*a1.w;
  }
  float* op = out + ((size_t)((b*SS + s)*NCH + n))*DD + hh*DH;
  *(float4*)(op)     = make_float4(acc2[0], acc2[1], acc2[2], acc2[3]);
  *(float4*)(op + 4) = make_float4(acc2[4], acc2[5], acc2[6], acc2[7]);
}

// ---------------------------------------------------------------------------
extern "C" void kernel_launch(void* const* d_in, const int* in_sizes, int n_in,
                              void* d_out, int out_size, void* d_ws, size_t ws_size,
                              hipStream_t stream) {
  (void)in_sizes; (void)n_in; (void)out_size; (void)ws_size;
  const float* x   = (const float*)d_in[0];
  const float* ox  = (const float*)d_in[1];
  const float* sW  = (const float*)d_in[2];
  const float* sb  = (const float*)d_in[3];
  const float* Wq  = (const float*)d_in[4];
  const float* Wk  = (const float*)d_in[5];
  const float* Wv  = (const float*)d_in[6];
  const float* Wo  = (const float*)d_in[7];
  const float* g1  = (const float*)d_in[8];
  const float* b1n = (const float*)d_in[9];
  const float* g2  = (const float*)d_in[10];
  const float* b2n = (const float*)d_in[11];
  const float* W1  = (const float*)d_in[12];
  const float* bf1 = (const float*)d_in[13];
  const float* W2  = (const float*)d_in[14];
  const float* bf2 = (const float*)d_in[15];
  float* out = (float*)d_out;
  float* ws  = (float*)d_ws;

  decomp_kernel<<<BB*NCH, 256, 0, stream>>>(x, ws);
  prep_kernel<<<1, 1024, 0, stream>>>(ox, sb, g1, b1n, Wk, Wv, ws);
  expert_kernel<<<BB*NCH, 1024, 0, stream>>>(ws, sW, sb, Wq, Wk, Wv, Wo,
                                             g1, b1n, g2, b2n, W1, bf1, W2, bf2, out);
}

// Round 3
// 235.584 us; speedup vs baseline: 1.0355x; 1.0355x over previous
//
#include <hip/hip_runtime.h>
#include <math.h>

#define BB 16
#define SS 256
#define CC 17
#define NCH 16
#define DD 32
#define DFFN 64
#define HH 4
#define DH 8
#define EE 4

// ws layout (4-byte units):
//  [16 ..143]  K0[e][d]   [144..271] V0[e][d]
//  [512..66047]  XNS[b][s][n]
//  ints at WS_SPI: SP[b][p] (4096), OFF[b][e] (64)
//  WS_Q:   q fp32, prescaled by 1/sqrt(8)*log2(e)   [pos][hh][8]   (2097152 floats)
//  WS_KVU: k/v packed bf16 as uints: [(b,n)][p][hh][k:4 v:4]       (2097152 uints)
#define WS_K0 16
#define WS_V0 144
#define WS_XNS 512
#define WS_SPI (WS_XNS + BB*SS*NCH)          // 66048
#define WS_Q   (WS_SPI + BB*SS + 64)         // 70208 (16B aligned)
#define WS_KVU (WS_Q + BB*SS*NCH*DD)         // 2167360

#define PRE 0.51006977f   // (1/sqrt(8)) * log2(e)

__device__ __forceinline__ float bl(unsigned u){ return __uint_as_float(u << 16); }
__device__ __forceinline__ float bh(unsigned u){ return __uint_as_float(u & 0xffff0000u); }
__device__ __forceinline__ unsigned pk2(float a, float b){
  unsigned ua = __float_as_uint(a), ub = __float_as_uint(b);
  ua += 0x7fffu + ((ua >> 16) & 1u);
  ub += 0x7fffu + ((ub >> 16) & 1u);
  return (ua >> 16) | (ub & 0xffff0000u);
}

// ---------------------------------------------------------------------------
// Kernel 1: seasonal-trend decomposition per (b, channel). 2-way split DFT,
// wave-shfl top-4 (no barriers), premultiplied irfft table.
// ---------------------------------------------------------------------------
__global__ void decomp_kernel(const float* __restrict__ x, float* __restrict__ ws) {
  const int b = blockIdx.x / NCH;
  const int c = blockIdx.x % NCH;
  const int t = threadIdx.x;  // 256
  __shared__ float xs[SS];
  __shared__ float pr[256], pi[256];
  __shared__ float amp[129];
  __shared__ float2 YY[129];
  __shared__ float sth;
  xs[t] = x[(b*SS + t)*CC + c];
  __syncthreads();
  const float TH0 = 0.024543692606170259f;  // 2*pi/256
  {
    const int f = (t & 127) + 1;
    const int half = t >> 7;
    float s1, c1; sincosf(TH0*(float)f, &s1, &c1);
    const int ph0 = (f * half * 128) & 255;
    float cr, si; sincosf(TH0*(float)ph0, &si, &cr);
    float xr = 0.f, xi = 0.f;
    for (int s2 = 0; s2 < 128; ++s2) {
      float xvv = xs[half*128 + s2];
      xr += xvv * cr;
      xi -= xvv * si;
      float nc = cr*c1 - si*s1;
      si = si*c1 + cr*s1;
      cr = nc;
    }
    pr[t] = xr; pi[t] = xi;
  }
  __syncthreads();
  if (t < 128) {
    float xr = pr[t] + pr[t+128];
    float xi = pi[t] + pi[t+128];
    pr[t] = xr; pi[t] = xi;          // now indexed by f-1
    amp[t+1] = sqrtf(xr*xr + xi*xi);
  }
  __syncthreads();
  if (t < 64) {   // wave 0: top-4 knockout, no barriers
    float a0 = amp[t+1], a1 = amp[t+65];
    int i0 = t+1, i1 = t+65;
    float th = -1e30f;
    for (int r = 0; r < 4; ++r) {
      float mv = (a0 > a1) ? a0 : a1;
      int   mi = (a0 > a1) ? i0 : i1;
      for (int off = 32; off > 0; off >>= 1) {
        float ov = __shfl_xor(mv, off);
        int   oi = __shfl_xor(mi, off);
        if (ov > mv || (ov == mv && oi < mi)) { mv = ov; mi = oi; }
      }
      th = mv;
      if (mi == i0) a0 = -1e30f;
      if (mi == i1) a1 = -1e30f;
    }
    if (t == 0) sth = th;
  }
  __syncthreads();
  const float th = sth;
  if (t < 128) {
    const int f = t + 1;
    float wgt = (amp[f] >= th) ? ((f == 128) ? 1.0f : 2.0f) * (1.0f/256.0f) : 0.0f;
    YY[f] = make_float2(wgt * pr[t], wgt * pi[t]);
  }
  __syncthreads();
  // irfft at s = t
  float s1, c1; sincosf(TH0*(float)t, &s1, &c1);
  float cr = c1, si = s1, acc = 0.f;
  for (int f = 1; f <= 128; ++f) {
    float2 y = YY[f];
    acc += y.x*cr - y.y*si;
    float nc = cr*c1 - si*s1;
    si = si*c1 + cr*s1;
    cr = nc;
  }
  const float season = acc;
  float s4 = 0.f, s8 = 0.f, s12 = 0.f;
  #pragma unroll
  for (int j = 0; j < 4; ++j)  { int p = t + j - 1; p = p < 0 ? 0 : (p > SS-1 ? SS-1 : p); s4  += xs[p]; }
  #pragma unroll
  for (int j = 0; j < 8; ++j)  { int p = t + j - 3; p = p < 0 ? 0 : (p > SS-1 ? SS-1 : p); s8  += xs[p]; }
  #pragma unroll
  for (int j = 0; j < 12; ++j) { int p = t + j - 5; p = p < 0 ? 0 : (p > SS-1 ? SS-1 : p); s12 += xs[p]; }
  float trend = (s4 * 0.25f + s8 * 0.125f + s12 * (1.0f/12.0f)) * (1.0f/3.0f);
  ws[WS_XNS + (b*SS + t)*NCH + c] = xs[t] + season + trend;
}

// ---------------------------------------------------------------------------
// Kernel 2: prep (grid 16, one block per b): global min/max, assignment,
// sorted lists; block 0 also computes k0/v0.
// ---------------------------------------------------------------------------
__global__ void prep_kernel(const float* __restrict__ ox, const float* __restrict__ sb,
                            const float* __restrict__ g1, const float* __restrict__ bb1,
                            const float* __restrict__ Wk, const float* __restrict__ Wv,
                            float* __restrict__ ws) {
  const int b = blockIdx.x;
  const int t = threadIdx.x;  // 256
  __shared__ float red[8];
  __shared__ int asg[SS];
  __shared__ int cnt[EE];
  __shared__ float z0[EE*DD];
  float mn = 3e38f, mx = -3e38f;
  for (int i = t; i < BB*SS; i += 256) {
    float v = ox[2*i + 1];
    mn = fminf(mn, v); mx = fmaxf(mx, v);
  }
  for (int off = 32; off > 0; off >>= 1) {
    mn = fminf(mn, __shfl_xor(mn, off));
    mx = fmaxf(mx, __shfl_xor(mx, off));
  }
  if ((t & 63) == 0) { red[(t>>6)*2] = mn; red[(t>>6)*2+1] = mx; }
  __syncthreads();
  mn = fminf(fminf(red[0], red[2]), fminf(red[4], red[6]));
  mx = fmaxf(fmaxf(red[1], red[3]), fmaxf(red[5], red[7]));
  const float step = (mx - mn) * 0.25f;
  const float e1 = mn + step, e2 = mn + 2.f*step, e3 = mn + 3.f*step;
  float sc = ox[(b*SS + t)*2 + 1];
  asg[t] = (sc >= e1) + (sc >= e2) + (sc >= e3);
  __syncthreads();
  if (t < EE) {
    int c = 0;
    for (int s2 = 0; s2 < SS; ++s2) c += (asg[s2] == t);
    cnt[t] = c;
  }
  __syncthreads();
  int* SPw  = (int*)ws + WS_SPI;
  int* OFFw = SPw + BB*SS;
  if (t < EE) {
    int off = 0;
    for (int i = 0; i < t; ++i) off += cnt[i];
    OFFw[b*EE + t] = off;
    int kp = off;
    for (int s2 = 0; s2 < SS; ++s2) if (asg[s2] == t) SPw[b*SS + (kp++)] = s2;
  }
  if (t < 128) {
    int ee = t >> 5, d = t & 31;
    float m = 0.f;
    for (int i = 0; i < DD; ++i) m += sb[i];
    m *= (1.0f/DD);
    float var = 0.f;
    for (int i = 0; i < DD; ++i) { float df = sb[i]-m; var += df*df; }
    var *= (1.0f/DD);
    float rs = rsqrtf(var + 1e-5f);
    z0[ee*DD + d] = (sb[d]-m)*rs*g1[ee*DD+d] + bb1[ee*DD+d];
  }
  __syncthreads();
  if (b == 0 && t < 128) {
    int ee = t >> 5, d = t & 31;
    float k0 = 0.f, v0 = 0.f;
    for (int i = 0; i < DD; ++i) {
      float zz = z0[ee*DD + i];
      k0 += zz * Wk[ee*DD*DD + i*DD + d];
      v0 += zz * Wv[ee*DD*DD + i*DD + d];
    }
    ws[WS_K0 + ee*DD + d] = k0;
    ws[WS_V0 + ee*DD + d] = v0;
  }
}

// ---------------------------------------------------------------------------
// Kernel 3: qkv — thread = (position, head-slice). q fp32 (prescaled),
// k/v packed bf16 to ws.
// ---------------------------------------------------------------------------
__launch_bounds__(256, 4)
__global__ void qkv_kernel(float* __restrict__ ws,
    const float* __restrict__ sW, const float* __restrict__ sb,
    const float* __restrict__ Wq, const float* __restrict__ Wk,
    const float* __restrict__ Wv,
    const float* __restrict__ g1, const float* __restrict__ bb1) {
  const int g = blockIdx.x*256 + threadIdx.x;
  const int hh = g & 3;
  const int pos = g >> 2;               // (b,p,n)
  const int n = pos & 15;
  const int p = (pos >> 4) & 255;
  const int b = pos >> 12;
  const int* SP  = (const int*)ws + WS_SPI;
  const int* OFF = SP + BB*SS;
  const int o1 = OFF[b*4+1], o2 = OFF[b*4+2], o3 = OFF[b*4+3];
  const int e = (p >= o1) + (p >= o2) + (p >= o3);
  const int s = SP[b*SS + p];
  const float xv = ws[WS_XNS + (b*SS + s)*NCH + n];

  float h[DD];
  #pragma unroll
  for (int d = 0; d < DD; ++d) h[d] = xv * sW[d] + sb[d];
  float m = 0.f;
  #pragma unroll
  for (int d = 0; d < DD; ++d) m += h[d];
  m *= (1.0f/DD);
  float var = 0.f;
  #pragma unroll
  for (int d = 0; d < DD; ++d) { float df = h[d]-m; var += df*df; }
  var *= (1.0f/DD);
  float rs = rsqrtf(var + 1e-5f);
  float z[DD];
  #pragma unroll
  for (int d = 0; d < DD; ++d) z[d] = (h[d]-m)*rs*g1[e*DD+d] + bb1[e*DD+d];

  const float* wqp = Wq + e*DD*DD + hh*DH;
  const float* wkp = Wk + e*DD*DD + hh*DH;
  const float* wvp = Wv + e*DD*DD + hh*DH;
  float q[DH]  = {0,0,0,0,0,0,0,0};
  float kk[DH] = {0,0,0,0,0,0,0,0};
  float vv[DH] = {0,0,0,0,0,0,0,0};
  #pragma unroll
  for (int i = 0; i < DD; ++i) {
    float zz = z[i];
    float4 a0 = *(const float4*)(wqp + i*DD);
    float4 a1 = *(const float4*)(wqp + i*DD + 4);
    q[0]+=zz*a0.x; q[1]+=zz*a0.y; q[2]+=zz*a0.z; q[3]+=zz*a0.w;
    q[4]+=zz*a1.x; q[5]+=zz*a1.y; q[6]+=zz*a1.z; q[7]+=zz*a1.w;
    float4 b0 = *(const float4*)(wkp + i*DD);
    float4 b1v = *(const float4*)(wkp + i*DD + 4);
    kk[0]+=zz*b0.x; kk[1]+=zz*b0.y; kk[2]+=zz*b0.z; kk[3]+=zz*b0.w;
    kk[4]+=zz*b1v.x; kk[5]+=zz*b1v.y; kk[6]+=zz*b1v.z; kk[7]+=zz*b1v.w;
    float4 c0 = *(const float4*)(wvp + i*DD);
    float4 c1v = *(const float4*)(wvp + i*DD + 4);
    vv[0]+=zz*c0.x; vv[1]+=zz*c0.y; vv[2]+=zz*c0.z; vv[3]+=zz*c0.w;
    vv[4]+=zz*c1v.x; vv[5]+=zz*c1v.y; vv[6]+=zz*c1v.z; vv[7]+=zz*c1v.w;
  }
  float* qp = ws + WS_Q + pos*32 + hh*DH;
  ((float4*)qp)[0] = make_float4(q[0]*PRE, q[1]*PRE, q[2]*PRE, q[3]*PRE);
  ((float4*)qp)[1] = make_float4(q[4]*PRE, q[5]*PRE, q[6]*PRE, q[7]*PRE);
  unsigned* kvg = (unsigned*)ws + WS_KVU + ((b*NCH + n)*SS + p)*32 + hh*8;
  ((uint4*)kvg)[0] = make_uint4(pk2(kk[0],kk[1]), pk2(kk[2],kk[3]), pk2(kk[4],kk[5]), pk2(kk[6],kk[7]));
  ((uint4*)kvg)[1] = make_uint4(pk2(vv[0],vv[1]), pk2(vv[2],vv[3]), pk2(vv[4],vv[5]), pk2(vv[6],vv[7]));
}

// ---------------------------------------------------------------------------
// Kernel 4: attention + Wo + FFN. Grid (b,n,quarter) = 1024 blocks x 256.
// Thread = (p_local in quarter, head). LDS 33 KB -> 4 blocks/CU.
// ---------------------------------------------------------------------------
__launch_bounds__(256, 4)
__global__ void attn_ffn_kernel(const float* __restrict__ ws,
    const float* __restrict__ sW, const float* __restrict__ sb,
    const float* __restrict__ Wo,
    const float* __restrict__ g2, const float* __restrict__ bb2,
    const float* __restrict__ W1, const float* __restrict__ b1,
    const float* __restrict__ W2, const float* __restrict__ b2,
    float* __restrict__ out) {
  const int blk = blockIdx.x;
  const int quarter = blk & 3;
  const int n = (blk >> 2) & 15;
  const int b = blk >> 6;
  const int t = threadIdx.x;
  const int pl = t >> 2;        // 0..63
  const int hh = t & 3;
  const int p = quarter*64 + pl;
  __shared__ unsigned lds[8448];   // kv: [0,8192); scratch aliases after attn
  float* fl = (float*)lds;

  const unsigned* src = (const unsigned*)ws + WS_KVU + (b*NCH + n)*8192;
  #pragma unroll
  for (int i = 0; i < 8; ++i) {
    int idx = (i*256 + t)*4;
    *(uint4*)&lds[idx] = *(const uint4*)&src[idx];
  }

  const int* SP  = (const int*)ws + WS_SPI;
  const int* OFF = SP + BB*SS;
  const int o1 = OFF[b*4+1], o2 = OFF[b*4+2], o3 = OFF[b*4+3];
  const int e = (p >= o1) + (p >= o2) + (p >= o3);
  const int beg = (e==0) ? 0  : ((e==1) ? o1 : ((e==2) ? o2 : o3));
  const int end = (e==0) ? o1 : ((e==1) ? o2 : ((e==2) ? o3 : SS));
  const int s = SP[b*SS + p];

  float q[DH];
  {
    const float* qp = ws + WS_Q + ((b*SS + p)*NCH + n)*32 + hh*DH;
    float4 qa = ((const float4*)qp)[0];
    float4 qb = ((const float4*)qp)[1];
    q[0]=qa.x; q[1]=qa.y; q[2]=qa.z; q[3]=qa.w;
    q[4]=qb.x; q[5]=qb.y; q[6]=qb.z; q[7]=qb.w;
  }
  float s0 = 0.f;
  #pragma unroll
  for (int d = 0; d < DH; ++d) s0 += q[d] * ws[WS_K0 + e*DD + hh*DH + d];
  float v0s[DH];
  #pragma unroll
  for (int d = 0; d < DH; ++d) v0s[d] = ws[WS_V0 + e*DD + hh*DH + d];
  __syncthreads();

  float wsum = 0.f;
  float o[DH] = {0,0,0,0,0,0,0,0};
  for (int j = beg; j < end; ++j) {
    uint4 ku = *(const uint4*)&lds[j*32 + hh*8];
    uint4 vu = *(const uint4*)&lds[j*32 + hh*8 + 4];
    float a = q[0]*bl(ku.x) + q[1]*bh(ku.x) + q[2]*bl(ku.y) + q[3]*bh(ku.y)
            + q[4]*bl(ku.z) + q[5]*bh(ku.z) + q[6]*bl(ku.w) + q[7]*bh(ku.w);
    float w = __builtin_amdgcn_exp2f(a);
    wsum += w;
    o[0]+=w*bl(vu.x); o[1]+=w*bh(vu.x); o[2]+=w*bl(vu.y); o[3]+=w*bh(vu.y);
    o[4]+=w*bl(vu.z); o[5]+=w*bh(vu.z); o[6]+=w*bl(vu.w); o[7]+=w*bh(vu.w);
  }
  const int nmis = SS - (end - beg);
  float w0 = (float)nmis * __builtin_amdgcn_exp2f(s0);
  wsum += w0;
  #pragma unroll
  for (int d = 0; d < DH; ++d) o[d] += w0 * v0s[d];
  float inv = 1.0f / wsum;
  #pragma unroll
  for (int d = 0; d < DH; ++d) o[d] *= inv;
  __syncthreads();   // kv reads complete before scratch overwrite

  // o scratch: [0, 2112) stride 33
  #pragma unroll
  for (int d = 0; d < DH; ++d) fl[pl*33 + hh*DH + d] = o[d];
  __syncthreads();

  // Wo + residual -> h2 scratch [2112, 4224) stride 33
  const float xv = ws[WS_XNS + (b*SS + s)*NCH + n];
  float acc[DH];
  #pragma unroll
  for (int d = 0; d < DH; ++d) acc[d] = xv * sW[hh*DH + d] + sb[hh*DH + d];
  const float* wop = Wo + e*DD*DD + hh*DH;
  #pragma unroll
  for (int i = 0; i < DD; ++i) {
    float ov = fl[pl*33 + i];
    float4 a0 = *(const float4*)(wop + i*DD);
    float4 a1 = *(const float4*)(wop + i*DD + 4);
    acc[0]+=ov*a0.x; acc[1]+=ov*a0.y; acc[2]+=ov*a0.z; acc[3]+=ov*a0.w;
    acc[4]+=ov*a1.x; acc[5]+=ov*a1.y; acc[6]+=ov*a1.z; acc[7]+=ov*a1.w;
  }
  #pragma unroll
  for (int d = 0; d < DH; ++d) fl[2112 + pl*33 + hh*DH + d] = acc[d];
  __syncthreads();

  float h2[DD];
  #pragma unroll
  for (int i = 0; i < DD; ++i) h2[i] = fl[2112 + pl*33 + i];
  float m = 0.f;
  #pragma unroll
  for (int d = 0; d < DD; ++d) m += h2[d];
  m *= (1.0f/DD);
  float var = 0.f;
  #pragma unroll
  for (int d = 0; d < DD; ++d) { float df = h2[d]-m; var += df*df; }
  var *= (1.0f/DD);
  float rs = rsqrtf(var + 1e-5f);
  float z[DD];
  #pragma unroll
  for (int d = 0; d < DD; ++d) z[d] = (h2[d]-m)*rs*g2[e*DD+d] + bb2[e*DD+d];
  float hres[DH];
  #pragma unroll
  for (int d = 0; d < DH; ++d) hres[d] = h2[hh*DH + d];

  // FFN1: f[hh*16 .. +16) -> f scratch [4224, 8384) stride 65
  const float* w1p = W1 + e*DD*DFFN + hh*16;
  float f[16];
  #pragma unroll
  for (int j = 0; j < 16; ++j) f[j] = 0.f;
  #pragma unroll
  for (int i = 0; i < DD; ++i) {
    float zz = z[i];
    float4 a0 = *(const float4*)(w1p + i*DFFN);
    float4 a1 = *(const float4*)(w1p + i*DFFN + 4);
    float4 a2 = *(const float4*)(w1p + i*DFFN + 8);
    float4 a3 = *(const float4*)(w1p + i*DFFN + 12);
    f[0]+=zz*a0.x; f[1]+=zz*a0.y; f[2]+=zz*a0.z; f[3]+=zz*a0.w;
    f[4]+=zz*a1.x; f[5]+=zz*a1.y; f[6]+=zz*a1.z; f[7]+=zz*a1.w;
    f[8]+=zz*a2.x; f[9]+=zz*a2.y; f[10]+=zz*a2.z; f[11]+=zz*a2.w;
    f[12]+=zz*a3.x; f[13]+=zz*a3.y; f[14]+=zz*a3.z; f[15]+=zz*a3.w;
  }
  #pragma unroll
  for (int j = 0; j < 16; ++j) {
    f[j] = fmaxf(f[j] + b1[e*DFFN + hh*16 + j], 0.0f);
    fl[4224 + pl*65 + hh*16 + j] = f[j];
  }
  __syncthreads();

  // FFN2 + residual + b2
  const float* w2p = W2 + e*DFFN*DD + hh*DH;
  float acc2[DH];
  #pragma unroll
  for (int d = 0; d < DH; ++d) acc2[d] = hres[d] + b2[e*DD + hh*DH + d];
  for (int j = 0; j < DFFN; ++j) {
    float fj = fl[4224 + pl*65 + j];
    float4 a0 = *(const float4*)(w2p + j*DD);
    float4 a1 = *(const float4*)(w2p + j*DD + 4);
    acc2[0]+=fj*a0.x; acc2[1]+=fj*a0.y; acc2[2]+=fj*a0.z; acc2[3]+=fj*a0.w;
    acc2[4]+=fj*a1.x; acc2[5]+=fj*a1.y; acc2[6]+=fj*a1.z; acc2[7]+=fj*a1.w;
  }
  float* op = out + ((size_t)((b*SS + s)*NCH + n))*DD + hh*DH;
  *(float4*)(op)     = make_float4(acc2[0], acc2[1], acc2[2], acc2[3]);
  *(float4*)(op + 4) = make_float4(acc2[4], acc2[5], acc2[6], acc2[7]);
}

// ---------------------------------------------------------------------------
extern "C" void kernel_launch(void* const* d_in, const int* in_sizes, int n_in,
                              void* d_out, int out_size, void* d_ws, size_t ws_size,
                              hipStream_t stream) {
  (void)in_sizes; (void)n_in; (void)out_size; (void)ws_size;
  const float* x   = (const float*)d_in[0];
  const float* ox  = (const float*)d_in[1];
  const float* sW  = (const float*)d_in[2];
  const float* sb  = (const float*)d_in[3];
  const float* Wq  = (const float*)d_in[4];
  const float* Wk  = (const float*)d_in[5];
  const float* Wv  = (const float*)d_in[6];
  const float* Wo  = (const float*)d_in[7];
  const float* g1  = (const float*)d_in[8];
  const float* b1n = (const float*)d_in[9];
  const float* g2  = (const float*)d_in[10];
  const float* b2n = (const float*)d_in[11];
  const float* W1  = (const float*)d_in[12];
  const float* bf1 = (const float*)d_in[13];
  const float* W2  = (const float*)d_in[14];
  const float* bf2 = (const float*)d_in[15];
  float* out = (float*)d_out;
  float* ws  = (float*)d_ws;

  decomp_kernel<<<BB*NCH, 256, 0, stream>>>(x, ws);
  prep_kernel<<<BB, 256, 0, stream>>>(ox, sb, g1, b1n, Wk, Wv, ws);
  qkv_kernel<<<BB*SS*NCH/64, 256, 0, stream>>>(ws, sW, sb, Wq, Wk, Wv, g1, b1n);
  attn_ffn_kernel<<<BB*NCH*4, 256, 0, stream>>>(ws, sW, sb, Wo, g2, b2n,
                                                W1, bf1, W2, bf2, out);
}

// Round 5
// 192.762 us; speedup vs baseline: 1.2655x; 1.2222x over previous
//
#include <hip/hip_runtime.h>
#include <math.h>

#define BB 16
#define SS 256
#define CC 17
#define NCH 16
#define DD 32
#define DFFN 64
#define HH 4
#define DH 8
#define EE 4

// ws layout (4-byte units):
//  [16 ..143]  K0[e][d]   [144..271] V0[e][d]
//  [512..66047]  XNS[b][s][n]
//  ints at WS_SPI: SP[b][p] (4096), OFF[b][e] (64)
//  WS_Q:   q fp32, prescaled by 1/sqrt(8)*log2(e)   [(b,p,n)][hh][8]
//  WS_KVU: k/v packed f16 as uints: [(b,n)][p][hh][k:4u v:4u]
#define WS_K0 16
#define WS_V0 144
#define WS_XNS 512
#define WS_SPI (WS_XNS + BB*SS*NCH)          // 66048
#define WS_Q   (WS_SPI + BB*SS + 64)         // 70208 (16B aligned)
#define WS_KVU (WS_Q + BB*SS*NCH*DD)         // 2167360

#define PRE 0.51006977f   // (1/sqrt(8)) * log2(e)

typedef _Float16 h8v __attribute__((ext_vector_type(8)));
typedef _Float16 h2v __attribute__((ext_vector_type(2)));

__device__ __forceinline__ unsigned pkh2(float a, float b) {
  __fp16 r2[2];
  *(decltype(__builtin_amdgcn_cvt_pkrtz(a, b))*)r2 = __builtin_amdgcn_cvt_pkrtz(a, b);
  unsigned u;
  __builtin_memcpy(&u, r2, 4);
  return u;
}

// ---------------------------------------------------------------------------
// Kernel 1: decomposition. 1024 thr: DFT = 128 freqs x 8 chunks,
// irfft = 256 samples x 4 freq-chunks; serial chains only 32 long.
// ---------------------------------------------------------------------------
__launch_bounds__(1024)
__global__ void decomp_kernel(const float* __restrict__ x, float* __restrict__ ws) {
  const int b = blockIdx.x / NCH;
  const int c = blockIdx.x % NCH;
  const int t = threadIdx.x;  // 1024
  __shared__ float xs[SS];
  __shared__ float prr[1024], pii[1024];
  __shared__ float amp[129];
  __shared__ float2 YY[129];
  __shared__ float sth;
  if (t < SS) xs[t] = x[(b*SS + t)*CC + c];
  __syncthreads();
  const float TH0 = 0.024543692606170259f;  // 2*pi/256
  {
    const int f = (t & 127) + 1;
    const int chunk = t >> 7;          // 0..7
    const int s0 = chunk * 32;
    const int ph0 = (f * s0) & 255;
    float si, cr; sincosf(TH0*(float)ph0, &si, &cr);
    float s1, c1; sincosf(TH0*(float)f, &s1, &c1);
    float xr = 0.f, xi = 0.f;
    #pragma unroll 4
    for (int k = 0; k < 32; ++k) {
      float xvv = xs[s0 + k];
      xr += xvv * cr;
      xi -= xvv * si;
      float nc = cr*c1 - si*s1;
      si = si*c1 + cr*s1;
      cr = nc;
    }
    prr[t] = xr; pii[t] = xi;
  }
  __syncthreads();
  if (t < 128) {
    float xr = 0.f, xi = 0.f;
    #pragma unroll
    for (int k2 = 0; k2 < 8; ++k2) { xr += prr[t + 128*k2]; xi += pii[t + 128*k2]; }
    prr[t] = xr; pii[t] = xi;
    amp[t+1] = sqrtf(xr*xr + xi*xi);
  }
  __syncthreads();
  if (t < 64) {   // wave 0: top-4 knockout
    float a0 = amp[t+1], a1 = amp[t+65];
    int i0 = t+1, i1 = t+65;
    float th = -1e30f;
    for (int r = 0; r < 4; ++r) {
      float mv = (a0 > a1) ? a0 : a1;
      int   mi = (a0 > a1) ? i0 : i1;
      for (int off = 32; off > 0; off >>= 1) {
        float ov = __shfl_xor(mv, off);
        int   oi = __shfl_xor(mi, off);
        if (ov > mv || (ov == mv && oi < mi)) { mv = ov; mi = oi; }
      }
      th = mv;
      if (mi == i0) a0 = -1e30f;
      if (mi == i1) a1 = -1e30f;
    }
    if (t == 0) sth = th;
  }
  __syncthreads();
  if (t < 128) {
    const int f = t + 1;
    float wgt = (amp[f] >= sth) ? ((f == 128) ? 1.0f : 2.0f) * (1.0f/256.0f) : 0.0f;
    YY[f] = make_float2(wgt * prr[t], wgt * pii[t]);
  }
  __syncthreads();
  {
    const int s = t & 255;
    const int fc = t >> 8;             // 0..3
    const int f0 = 1 + fc*32;
    const int ph0 = (s * f0) & 255;
    float si, cr; sincosf(TH0*(float)ph0, &si, &cr);
    float s1, c1; sincosf(TH0*(float)s, &s1, &c1);
    float acc = 0.f;
    #pragma unroll 4
    for (int k = 0; k < 32; ++k) {
      float2 y = YY[f0 + k];
      acc += y.x*cr - y.y*si;
      float nc = cr*c1 - si*s1;
      si = si*c1 + cr*s1;
      cr = nc;
    }
    prr[t] = acc;
  }
  __syncthreads();
  if (t < 256) {
    float season = prr[t] + prr[t+256] + prr[t+512] + prr[t+768];
    float s4 = 0.f, s8 = 0.f, s12 = 0.f;
    #pragma unroll
    for (int j = 0; j < 4; ++j)  { int p = t + j - 1; p = p < 0 ? 0 : (p > SS-1 ? SS-1 : p); s4  += xs[p]; }
    #pragma unroll
    for (int j = 0; j < 8; ++j)  { int p = t + j - 3; p = p < 0 ? 0 : (p > SS-1 ? SS-1 : p); s8  += xs[p]; }
    #pragma unroll
    for (int j = 0; j < 12; ++j) { int p = t + j - 5; p = p < 0 ? 0 : (p > SS-1 ? SS-1 : p); s12 += xs[p]; }
    float trend = (s4 * 0.25f + s8 * 0.125f + s12 * (1.0f/12.0f)) * (1.0f/3.0f);
    ws[WS_XNS + (b*SS + t)*NCH + c] = xs[t] + season + trend;
  }
}

// ---------------------------------------------------------------------------
// Kernel 2: prep (grid 16): min/max, assignment, sorted lists; k0/v0 on b=0.
// ---------------------------------------------------------------------------
__global__ void prep_kernel(const float* __restrict__ ox, const float* __restrict__ sb,
                            const float* __restrict__ g1, const float* __restrict__ bb1,
                            const float* __restrict__ Wk, const float* __restrict__ Wv,
                            float* __restrict__ ws) {
  const int b = blockIdx.x;
  const int t = threadIdx.x;  // 256
  __shared__ float red[8];
  __shared__ int asg[SS];
  __shared__ int cnt[EE];
  __shared__ float z0[EE*DD];
  float mn = 3e38f, mx = -3e38f;
  for (int i = t; i < BB*SS; i += 256) {
    float v = ox[2*i + 1];
    mn = fminf(mn, v); mx = fmaxf(mx, v);
  }
  for (int off = 32; off > 0; off >>= 1) {
    mn = fminf(mn, __shfl_xor(mn, off));
    mx = fmaxf(mx, __shfl_xor(mx, off));
  }
  if ((t & 63) == 0) { red[(t>>6)*2] = mn; red[(t>>6)*2+1] = mx; }
  __syncthreads();
  mn = fminf(fminf(red[0], red[2]), fminf(red[4], red[6]));
  mx = fmaxf(fmaxf(red[1], red[3]), fmaxf(red[5], red[7]));
  const float step = (mx - mn) * 0.25f;
  const float e1 = mn + step, e2 = mn + 2.f*step, e3 = mn + 3.f*step;
  float sc = ox[(b*SS + t)*2 + 1];
  asg[t] = (sc >= e1) + (sc >= e2) + (sc >= e3);
  __syncthreads();
  if (t < EE) {
    int c = 0;
    for (int s2 = 0; s2 < SS; ++s2) c += (asg[s2] == t);
    cnt[t] = c;
  }
  __syncthreads();
  int* SPw  = (int*)ws + WS_SPI;
  int* OFFw = SPw + BB*SS;
  if (t < EE) {
    int off = 0;
    for (int i = 0; i < t; ++i) off += cnt[i];
    OFFw[b*EE + t] = off;
    int kp = off;
    for (int s2 = 0; s2 < SS; ++s2) if (asg[s2] == t) SPw[b*SS + (kp++)] = s2;
  }
  if (b == 0 && t < 128) {
    int ee = t >> 5, d = t & 31;
    float m = 0.f;
    for (int i = 0; i < DD; ++i) m += sb[i];
    m *= (1.0f/DD);
    float var = 0.f;
    for (int i = 0; i < DD; ++i) { float df = sb[i]-m; var += df*df; }
    var *= (1.0f/DD);
    float rs = rsqrtf(var + 1e-5f);
    z0[ee*DD + d] = (sb[d]-m)*rs*g1[ee*DD+d] + bb1[ee*DD+d];
    __syncthreads();
    float k0 = 0.f, v0 = 0.f;
    for (int i = 0; i < DD; ++i) {
      float zz = z0[ee*DD + i];
      k0 += zz * Wk[ee*DD*DD + i*DD + d];
      v0 += zz * Wv[ee*DD*DD + i*DD + d];
    }
    ws[WS_K0 + ee*DD + d] = k0;
    ws[WS_V0 + ee*DD + d] = v0;
  }
}

// ---------------------------------------------------------------------------
// Kernel 3: qkv with f16 weights staged in LDS (24 KB, all 4 experts).
// ---------------------------------------------------------------------------
__launch_bounds__(256, 4)
__global__ void qkv_kernel(float* __restrict__ ws,
    const float* __restrict__ Wq, const float* __restrict__ Wk,
    const float* __restrict__ Wv,
    const float* __restrict__ g1, const float* __restrict__ bb1,
    const float* __restrict__ sW, const float* __restrict__ sb) {
  __shared__ _Float16 wl[12288];   // Wq [0,4096), Wk [4096,8192), Wv [8192,12288) halves
  unsigned* wu = (unsigned*)wl;
  const int t = threadIdx.x;
  #pragma unroll
  for (int i = 0; i < 8; ++i) {
    int idx = i*256 + t;
    float2 aq = *(const float2*)(Wq + idx*2); wu[idx]        = pkh2(aq.x, aq.y);
    float2 bq = *(const float2*)(Wk + idx*2); wu[2048 + idx] = pkh2(bq.x, bq.y);
    float2 cq = *(const float2*)(Wv + idx*2); wu[4096 + idx] = pkh2(cq.x, cq.y);
  }
  const int gI = blockIdx.x*256 + t;
  const int hh = gI & 3;
  const int pos = gI >> 2;               // (b,p,n)
  const int n = pos & 15;
  const int p = (pos >> 4) & 255;
  const int b = pos >> 12;
  const int* SP  = (const int*)ws + WS_SPI;
  const int* OFF = SP + BB*SS;
  const int o1 = OFF[b*4+1], o2 = OFF[b*4+2], o3 = OFF[b*4+3];
  const int e = (p >= o1) + (p >= o2) + (p >= o3);
  const int s = SP[b*SS + p];
  const float xv = ws[WS_XNS + (b*SS + s)*NCH + n];

  float h[DD];
  #pragma unroll
  for (int d = 0; d < DD; ++d) h[d] = xv * sW[d] + sb[d];
  float m = 0.f;
  #pragma unroll
  for (int d = 0; d < DD; ++d) m += h[d];
  m *= (1.0f/DD);
  float var = 0.f;
  #pragma unroll
  for (int d = 0; d < DD; ++d) { float df = h[d]-m; var += df*df; }
  var *= (1.0f/DD);
  float rs = rsqrtf(var + 1e-5f);
  float z[DD];
  #pragma unroll
  for (int d = 0; d < DD; ++d) z[d] = (h[d]-m)*rs*g1[e*DD+d] + bb1[e*DD+d];
  __syncthreads();

  float q[DH]  = {0,0,0,0,0,0,0,0};
  float kk[DH] = {0,0,0,0,0,0,0,0};
  float vv[DH] = {0,0,0,0,0,0,0,0};
  #pragma unroll
  for (int i = 0; i < DD; ++i) {
    float zz = z[i];
    h8v wq8 = *(const h8v*)&wl[(e*DD + i)*DD + hh*DH];
    h8v wk8 = *(const h8v*)&wl[4096 + (e*DD + i)*DD + hh*DH];
    h8v wv8 = *(const h8v*)&wl[8192 + (e*DD + i)*DD + hh*DH];
    #pragma unroll
    for (int d = 0; d < DH; ++d) {
      q[d]  += zz * (float)wq8[d];
      kk[d] += zz * (float)wk8[d];
      vv[d] += zz * (float)wv8[d];
    }
  }
  float* qp = ws + WS_Q + pos*32 + hh*DH;
  ((float4*)qp)[0] = make_float4(q[0]*PRE, q[1]*PRE, q[2]*PRE, q[3]*PRE);
  ((float4*)qp)[1] = make_float4(q[4]*PRE, q[5]*PRE, q[6]*PRE, q[7]*PRE);
  unsigned* kvg = (unsigned*)ws + WS_KVU + ((b*NCH + n)*SS + p)*32 + hh*8;
  ((uint4*)kvg)[0] = make_uint4(pkh2(kk[0],kk[1]), pkh2(kk[2],kk[3]), pkh2(kk[4],kk[5]), pkh2(kk[6],kk[7]));
  ((uint4*)kvg)[1] = make_uint4(pkh2(vv[0],vv[1]), pkh2(vv[2],vv[3]), pkh2(vv[4],vv[5]), pkh2(vv[6],vv[7]));
}

// ---------------------------------------------------------------------------
// Kernel 4: attn + Wo + FFN. Grid (b,n,half)=512 blocks x 512 thr (8 waves).
// Wave j handles sorted group (half + 2j) -> balanced blocks. Weights f16 in
// LDS (40 KB) staged before first barrier; kv 32 KB; scratch aliases kv.
// ---------------------------------------------------------------------------
__launch_bounds__(512, 4)
__global__ void attn_ffn_kernel(const float* __restrict__ ws,
    const float* __restrict__ sW, const float* __restrict__ sb,
    const float* __restrict__ Wo,
    const float* __restrict__ g2, const float* __restrict__ bb2,
    const float* __restrict__ W1, const float* __restrict__ b1,
    const float* __restrict__ W2, const float* __restrict__ b2,
    float* __restrict__ out) {
  const int blk = blockIdx.x;
  const int hq = blk & 1;
  const int n = (blk >> 1) & 15;
  const int b = blk >> 5;
  const int t = threadIdx.x;
  const int wj = t >> 6;        // wave 0..7
  const int lane = t & 63;
  const int pg = lane >> 2;     // 0..15
  const int hh = lane & 3;
  const int g = hq + 2*wj;      // sorted group 0..15, strided
  const int p = g*16 + pg;      // global sorted position
  const int pb = wj*16 + pg;    // local scratch index 0..127
  __shared__ unsigned lds[8192];       // kv; scratch aliases after attention
  __shared__ _Float16 wl[20480];       // Wo [0,4096) W1 [4096,12288) W2 [12288,20480)
  float* fl = (float*)lds;
  unsigned* ufl = lds;
  unsigned* wu = (unsigned*)wl;

  // stage kv (8192 uints)
  const unsigned* src = (const unsigned*)ws + WS_KVU + (b*NCH + n)*8192;
  #pragma unroll
  for (int i = 0; i < 4; ++i) {
    int idx = (i*512 + t)*4;
    *(uint4*)&lds[idx] = *(const uint4*)&src[idx];
  }
  // stage weights f16
  #pragma unroll
  for (int i = 0; i < 4; ++i) {
    int idx = i*512 + t;
    float2 v = *(const float2*)(Wo + idx*2);
    wu[idx] = pkh2(v.x, v.y);
  }
  #pragma unroll
  for (int i = 0; i < 8; ++i) {
    int idx = i*512 + t;
    float2 v = *(const float2*)(W1 + idx*2);
    wu[2048 + idx] = pkh2(v.x, v.y);
  }
  #pragma unroll
  for (int i = 0; i < 8; ++i) {
    int idx = i*512 + t;
    float2 v = *(const float2*)(W2 + idx*2);
    wu[6144 + idx] = pkh2(v.x, v.y);
  }

  const int* SP  = (const int*)ws + WS_SPI;
  const int* OFF = SP + BB*SS;
  const int o1 = OFF[b*4+1], o2 = OFF[b*4+2], o3 = OFF[b*4+3];
  const int e = (p >= o1) + (p >= o2) + (p >= o3);
  const int beg = (e==0) ? 0  : ((e==1) ? o1 : ((e==2) ? o2 : o3));
  const int end = (e==0) ? o1 : ((e==1) ? o2 : ((e==2) ? o3 : SS));
  const int s = SP[b*SS + p];

  float q[DH];
  {
    const float* qp = ws + WS_Q + ((b*SS + p)*NCH + n)*32 + hh*DH;
    float4 qa = ((const float4*)qp)[0];
    float4 qb = ((const float4*)qp)[1];
    q[0]=qa.x; q[1]=qa.y; q[2]=qa.z; q[3]=qa.w;
    q[4]=qb.x; q[5]=qb.y; q[6]=qb.z; q[7]=qb.w;
  }
  float s0 = 0.f;
  #pragma unroll
  for (int d = 0; d < DH; ++d) s0 += q[d] * ws[WS_K0 + e*DD + hh*DH + d];
  float v0s[DH];
  #pragma unroll
  for (int d = 0; d < DH; ++d) v0s[d] = ws[WS_V0 + e*DD + hh*DH + d];
  __syncthreads();   // kv + weights staged

  float wsum = 0.f;
  float o[DH] = {0,0,0,0,0,0,0,0};
  for (int jk = beg; jk < end; ++jk) {
    h8v kh = *(const h8v*)&lds[jk*32 + hh*8];
    h8v vh = *(const h8v*)&lds[jk*32 + hh*8 + 4];
    float a = q[0]*(float)kh[0] + q[1]*(float)kh[1] + q[2]*(float)kh[2] + q[3]*(float)kh[3]
            + q[4]*(float)kh[4] + q[5]*(float)kh[5] + q[6]*(float)kh[6] + q[7]*(float)kh[7];
    float w = __builtin_amdgcn_exp2f(a);
    wsum += w;
    #pragma unroll
    for (int d = 0; d < DH; ++d) o[d] += w * (float)vh[d];
  }
  const int nmis = SS - (end - beg);
  float w0 = (float)nmis * __builtin_amdgcn_exp2f(s0);
  wsum += w0;
  #pragma unroll
  for (int d = 0; d < DH; ++d) o[d] += w0 * v0s[d];
  float inv = 1.0f / wsum;
  #pragma unroll
  for (int d = 0; d < DH; ++d) o[d] *= inv;
  __syncthreads();   // all kv reads done; scratch may overwrite

  // o exchange: [pb][32] fp32, stride 33
  #pragma unroll
  for (int d = 0; d < DH; ++d) fl[pb*33 + hh*DH + d] = o[d];
  __syncthreads();

  // Wo + residual
  const float xv = ws[WS_XNS + (b*SS + s)*NCH + n];
  float acc[DH];
  #pragma unroll
  for (int d = 0; d < DH; ++d) acc[d] = xv * sW[hh*DH + d] + sb[hh*DH + d];
  #pragma unroll
  for (int i = 0; i < DD; ++i) {
    float ov = fl[pb*33 + i];
    h8v wo8 = *(const h8v*)&wl[(e*DD + i)*DD + hh*DH];
    #pragma unroll
    for (int d = 0; d < DH; ++d) acc[d] += ov * (float)wo8[d];
  }
  __syncthreads();   // o reads done; reuse region for h2
  #pragma unroll
  for (int d = 0; d < DH; ++d) fl[pb*33 + hh*DH + d] = acc[d];
  __syncthreads();

  float h2r[DD];
  #pragma unroll
  for (int i = 0; i < DD; ++i) h2r[i] = fl[pb*33 + i];
  float m = 0.f;
  #pragma unroll
  for (int d = 0; d < DD; ++d) m += h2r[d];
  m *= (1.0f/DD);
  float var = 0.f;
  #pragma unroll
  for (int d = 0; d < DD; ++d) { float df = h2r[d]-m; var += df*df; }
  var *= (1.0f/DD);
  float rs = rsqrtf(var + 1e-5f);
  float z[DD];
  #pragma unroll
  for (int d = 0; d < DD; ++d) z[d] = (h2r[d]-m)*rs*g2[e*DD+d] + bb2[e*DD+d];
  float hres[DH];
  #pragma unroll
  for (int d = 0; d < DH; ++d) hres[d] = h2r[hh*DH + d];
  __syncthreads();   // h2 reads done; reuse region for f

  // FFN1: f[hh*16 .. +16)
  float f[16];
  #pragma unroll
  for (int jf = 0; jf < 16; ++jf) f[jf] = 0.f;
  #pragma unroll
  for (int i = 0; i < DD; ++i) {
    float zz = z[i];
    h8v w1a = *(const h8v*)&wl[4096 + (e*DD + i)*DFFN + hh*16];
    h8v w1b = *(const h8v*)&wl[4096 + (e*DD + i)*DFFN + hh*16 + 8];
    #pragma unroll
    for (int d = 0; d < DH; ++d) {
      f[d]   += zz * (float)w1a[d];
      f[8+d] += zz * (float)w1b[d];
    }
  }
  #pragma unroll
  for (int jf = 0; jf < 16; ++jf)
    f[jf] = fmaxf(f[jf] + b1[e*DFFN + hh*16 + jf], 0.0f);
  #pragma unroll
  for (int jj = 0; jj < 8; ++jj)
    ufl[pb*33 + hh*8 + jj] = pkh2(f[2*jj], f[2*jj+1]);
  __syncthreads();

  // FFN2 + residual + b2
  float acc2[DH];
  #pragma unroll
  for (int d = 0; d < DH; ++d) acc2[d] = hres[d] + b2[e*DD + hh*DH + d];
  #pragma unroll
  for (int jj = 0; jj < 32; ++jj) {
    unsigned fu = ufl[pb*33 + jj];
    h2v fv;
    __builtin_memcpy(&fv, &fu, 4);
    float f0 = (float)fv[0], f1 = (float)fv[1];
    h8v w2a = *(const h8v*)&wl[12288 + (e*DFFN + 2*jj  )*DD + hh*DH];
    h8v w2b = *(const h8v*)&wl[12288 + (e*DFFN + 2*jj+1)*DD + hh*DH];
    #pragma unroll
    for (int d = 0; d < DH; ++d)
      acc2[d] += f0 * (float)w2a[d] + f1 * (float)w2b[d];
  }
  float* op = out + ((size_t)((b*SS + s)*NCH + n))*DD + hh*DH;
  *(float4*)(op)     = make_float4(acc2[0], acc2[1], acc2[2], acc2[3]);
  *(float4*)(op + 4) = make_float4(acc2[4], acc2[5], acc2[6], acc2[7]);
}

// ---------------------------------------------------------------------------
extern "C" void kernel_launch(void* const* d_in, const int* in_sizes, int n_in,
                              void* d_out, int out_size, void* d_ws, size_t ws_size,
                              hipStream_t stream) {
  (void)in_sizes; (void)n_in; (void)out_size; (void)ws_size;
  const float* x   = (const float*)d_in[0];
  const float* ox  = (const float*)d_in[1];
  const float* sW  = (const float*)d_in[2];
  const float* sb  = (const float*)d_in[3];
  const float* Wq  = (const float*)d_in[4];
  const float* Wk  = (const float*)d_in[5];
  const float* Wv  = (const float*)d_in[6];
  const float* Wo  = (const float*)d_in[7];
  const float* g1  = (const float*)d_in[8];
  const float* b1n = (const float*)d_in[9];
  const float* g2  = (const float*)d_in[10];
  const float* b2n = (const float*)d_in[11];
  const float* W1  = (const float*)d_in[12];
  const float* bf1 = (const float*)d_in[13];
  const float* W2  = (const float*)d_in[14];
  const float* bf2 = (const float*)d_in[15];
  float* out = (float*)d_out;
  float* ws  = (float*)d_ws;

  decomp_kernel<<<BB*NCH, 1024, 0, stream>>>(x, ws);
  prep_kernel<<<BB, 256, 0, stream>>>(ox, sb, g1, b1n, Wk, Wv, ws);
  qkv_kernel<<<BB*SS*NCH*4/256, 256, 0, stream>>>(ws, Wq, Wk, Wv, g1, b1n, sW, sb);
  attn_ffn_kernel<<<BB*NCH*2, 512, 0, stream>>>(ws, sW, sb, Wo, g2, b2n,
                                                W1, bf1, W2, bf2, out);
}